// Round 5
// baseline (18132.234 us; speedup 1.0000x reference)
//
#include <hip/hip_runtime.h>

typedef unsigned int u32_t;

#define S_LEN 2048
#define EDIM  1024
#define HDIM  1024
#define GDIM  4096   // 4*H

#define POISON 0xAAAAAAAAu

// ---------------------------------------------------------------------------
// Phase A: ix[t][r] = emb[tokens[t]] . W_ih[r] + b_ih[r] + b_hh[r]
// fp32 LDS-tiled GEMM, 64x64 tile, BK=16, 256 threads, 4x4 micro-tile. ~92us.
// (unchanged from the passing R2 kernel)
// ---------------------------------------------------------------------------
__global__ __launch_bounds__(256)
void ix_gemm(const int* __restrict__ tokens, const float* __restrict__ emb,
             const float* __restrict__ Wih, const float* __restrict__ bih,
             const float* __restrict__ bhh, float* __restrict__ ix)
{
    __shared__ float As[16][68];
    __shared__ float Bs[16][68];
    const int t0  = blockIdx.x * 64;
    const int r0  = blockIdx.y * 64;
    const int tid = threadIdx.x;
    const int tx  = tid & 15;          // n-direction
    const int ty  = tid >> 4;          // m-direction
    const int m_a = tid & 63;          // staging row
    const int k_a = (tid >> 6) << 2;   // staging k offset: 0,4,8,12

    const float* arow = emb + (size_t)tokens[t0 + m_a] * EDIM + k_a;
    const float* brow = Wih + (size_t)(r0 + m_a) * EDIM + k_a;

    float acc[4][4] = {};
    for (int kk = 0; kk < EDIM; kk += 16) {
        float4 av = *(const float4*)(arow + kk);
        float4 bv = *(const float4*)(brow + kk);
        __syncthreads();
        As[k_a + 0][m_a] = av.x; As[k_a + 1][m_a] = av.y;
        As[k_a + 2][m_a] = av.z; As[k_a + 3][m_a] = av.w;
        Bs[k_a + 0][m_a] = bv.x; Bs[k_a + 1][m_a] = bv.y;
        Bs[k_a + 2][m_a] = bv.z; Bs[k_a + 3][m_a] = bv.w;
        __syncthreads();
#pragma unroll
        for (int k = 0; k < 16; ++k) {
            float4 a = *(const float4*)&As[k][ty << 2];
            float4 b = *(const float4*)&Bs[k][tx << 2];
            acc[0][0] += a.x * b.x; acc[0][1] += a.x * b.y;
            acc[0][2] += a.x * b.z; acc[0][3] += a.x * b.w;
            acc[1][0] += a.y * b.x; acc[1][1] += a.y * b.y;
            acc[1][2] += a.y * b.z; acc[1][3] += a.y * b.w;
            acc[2][0] += a.z * b.x; acc[2][1] += a.z * b.y;
            acc[2][2] += a.z * b.z; acc[2][3] += a.z * b.w;
            acc[3][0] += a.w * b.x; acc[3][1] += a.w * b.y;
            acc[3][2] += a.w * b.z; acc[3][3] += a.w * b.w;
        }
    }
    const int n0 = r0 + (tx << 2);
    float b0 = bih[n0 + 0] + bhh[n0 + 0];
    float b1 = bih[n0 + 1] + bhh[n0 + 1];
    float b2 = bih[n0 + 2] + bhh[n0 + 2];
    float b3 = bih[n0 + 3] + bhh[n0 + 3];
#pragma unroll
    for (int i = 0; i < 4; ++i) {
        int m = t0 + (ty << 2) + i;
        float4 v = make_float4(acc[i][0] + b0, acc[i][1] + b1,
                               acc[i][2] + b2, acc[i][3] + b3);
        *(float4*)(ix + (size_t)m * GDIM + n0) = v;
    }
}

// ---------------------------------------------------------------------------
// Phase B: split-K recurrence. 1024 blocks x 256 threads; block b computes
// h[b]; wave q covers k in [256q, 256q+256). Lane holds ONE float4 of weights
// per gate (16 VGPRs total) -> natural register pressure ~50 VGPRs, UNDER the
// allocator's 8-wave/EU budget of 64, so nothing spills or sinks (R2-R4
// showed the allocator will spill/refetch rather than exceed that budget).
//
// Thread tid polls hslot[t-1][4*tid..4*tid+3] (poison protocol: d_ws is
// pre-poisoned 0xAAAAAAAA by the harness; producer canonicalizes an
// exact-poison h to 0.0f, so no hang). Retries re-read only missing dwords,
// throttled by s_sleep. One barrier per step; part[] is double-buffered.
// ---------------------------------------------------------------------------
__device__ __forceinline__ float fast_sigmoid(float x) {
    return 1.0f / (1.0f + __expf(-x));
}
__device__ __forceinline__ float fast_tanh(float x) {
    return 1.0f - 2.0f / (__expf(2.0f * x) + 1.0f);
}

__global__ __launch_bounds__(256)
void lstm_rec(const float* __restrict__ Whh,   // [4H, H]
              const float* __restrict__ ix,    // [S, 4H]
              u32_t* hslot,                    // [S][H] poison-init
              float* __restrict__ out)         // [H]
{
    const int tid  = threadIdx.x;
    const int q    = tid >> 6;                 // wave = k-quarter
    const int lane = tid & 63;
    const int b    = blockIdx.x;               // output index j
    const int kidx = tid << 2;                 // this thread's 4 k's

    __shared__ float4 part[2][4];              // [buf][wave] = {si,sf,sg,so}

    // 16 weight floats/lane, one float4 per gate. Coalesced loads.
    float4 wiv = *(const float4*)(Whh + (size_t)(0 * HDIM + b) * HDIM + kidx);
    float4 wfv = *(const float4*)(Whh + (size_t)(1 * HDIM + b) * HDIM + kidx);
    float4 wgv = *(const float4*)(Whh + (size_t)(2 * HDIM + b) * HDIM + kidx);
    float4 wov = *(const float4*)(Whh + (size_t)(3 * HDIM + b) * HDIM + kidx);
    // Light pin: fits the budget, so this is insurance against sinking, not
    // a fight with the allocator.
    asm volatile("" : "+v"(wiv.x), "+v"(wiv.y), "+v"(wiv.z), "+v"(wiv.w));
    asm volatile("" : "+v"(wfv.x), "+v"(wfv.y), "+v"(wfv.z), "+v"(wfv.w));
    asm volatile("" : "+v"(wgv.x), "+v"(wgv.y), "+v"(wgv.z), "+v"(wgv.w));
    asm volatile("" : "+v"(wov.x), "+v"(wov.y), "+v"(wov.z), "+v"(wov.w));

    const bool comb = (q == 0) && (lane < 4);  // combine lanes: gate = lane
    float c   = 0.0f;                          // lives in wave0 lane0
    float ixv = 0.0f;                          // this gate's ix[t] value
    if (comb) ixv = ix[(size_t)lane * HDIM + b];   // t = 0

    u32_t p0 = POISON, p1 = POISON, p2 = POISON, p3 = POISON;

    for (int t = 0; t < S_LEN; ++t) {
        float4 h4;
        if (t == 0) {
            h4 = make_float4(0.f, 0.f, 0.f, 0.f);
        } else {
            const u32_t* src = hslot + (size_t)(t - 1) * HDIM + kidx;
            for (;;) {
                bool m0 = (p0 == POISON), m1 = (p1 == POISON);
                bool m2 = (p2 == POISON), m3 = (p3 == POISON);
                if (!(m0 | m1 | m2 | m3)) break;
                if (m0) p0 = __hip_atomic_load(src + 0, __ATOMIC_RELAXED, __HIP_MEMORY_SCOPE_AGENT);
                if (m1) p1 = __hip_atomic_load(src + 1, __ATOMIC_RELAXED, __HIP_MEMORY_SCOPE_AGENT);
                if (m2) p2 = __hip_atomic_load(src + 2, __ATOMIC_RELAXED, __HIP_MEMORY_SCOPE_AGENT);
                if (m3) p3 = __hip_atomic_load(src + 3, __ATOMIC_RELAXED, __HIP_MEMORY_SCOPE_AGENT);
                __builtin_amdgcn_s_sleep(1);   // throttle L3 poll storm
            }
            h4 = make_float4(__uint_as_float(p0), __uint_as_float(p1),
                             __uint_as_float(p2), __uint_as_float(p3));
        }

        // 16 FMAs: 4-wide dot per gate.
        float si = wiv.x*h4.x + wiv.y*h4.y + wiv.z*h4.z + wiv.w*h4.w;
        float sf = wfv.x*h4.x + wfv.y*h4.y + wfv.z*h4.z + wfv.w*h4.w;
        float sg = wgv.x*h4.x + wgv.y*h4.y + wgv.z*h4.z + wgv.w*h4.w;
        float so = wov.x*h4.x + wov.y*h4.y + wov.z*h4.z + wov.w*h4.w;

        // 64-lane butterfly all-reduce, 4 interleaved chains.
#pragma unroll
        for (int s = 32; s > 0; s >>= 1) {
            si += __shfl_xor(si, s, 64);
            sf += __shfl_xor(sf, s, 64);
            sg += __shfl_xor(sg, s, 64);
            so += __shfl_xor(so, s, 64);
        }

        if (lane == 0) part[t & 1][q] = make_float4(si, sf, sg, so);
        __syncthreads();   // single barrier per step (part[] double-buffered)

        if (comb) {
            const float* P = (const float*)&part[t & 1][0];
            float s = P[lane] + P[4 + lane] + P[8 + lane] + P[12 + lane] + ixv;
            // gate order i,f,g,o: lane 2 (g) gets tanh, others sigmoid
            float r = (lane == 2) ? fast_tanh(s) : fast_sigmoid(s);
            float r1 = __shfl(r, 1);
            float r2 = __shfl(r, 2);
            float r3 = __shfl(r, 3);
            if (lane == 0) {
                c = r1 * c + r * r2;           // sig(f)*c + sig(i)*tanh(g)
                float h = r3 * fast_tanh(c);   // sig(o)*tanh(c)
                u32_t hb = __float_as_uint(h);
                if (hb == POISON) hb = 0u;     // hang-proof canonicalization
                __hip_atomic_store(hslot + (size_t)t * HDIM + b, hb,
                                   __ATOMIC_RELAXED, __HIP_MEMORY_SCOPE_AGENT);
                if (t == S_LEN - 1) out[b] = h;
            }
            // prefetch next step's ix value (hides its L2/HBM latency)
            int tn = (t + 1 < S_LEN) ? (t + 1) : t;
            ixv = ix[(size_t)tn * GDIM + (size_t)lane * HDIM + b];
        }

        // Speculative prefetch of next step's 4 h-dwords; stragglers get
        // re-polled at the top of the next iteration.
        const u32_t* nsrc = hslot + (size_t)t * HDIM + kidx;
        p0 = __hip_atomic_load(nsrc + 0, __ATOMIC_RELAXED, __HIP_MEMORY_SCOPE_AGENT);
        p1 = __hip_atomic_load(nsrc + 1, __ATOMIC_RELAXED, __HIP_MEMORY_SCOPE_AGENT);
        p2 = __hip_atomic_load(nsrc + 2, __ATOMIC_RELAXED, __HIP_MEMORY_SCOPE_AGENT);
        p3 = __hip_atomic_load(nsrc + 3, __ATOMIC_RELAXED, __HIP_MEMORY_SCOPE_AGENT);
    }
}

// ---------------------------------------------------------------------------
extern "C" void kernel_launch(void* const* d_in, const int* in_sizes, int n_in,
                              void* d_out, int out_size, void* d_ws, size_t ws_size,
                              hipStream_t stream) {
    const int*   tokens = (const int*)  d_in[0];
    const float* emb    = (const float*)d_in[1];
    const float* Wih    = (const float*)d_in[2];
    const float* Whh    = (const float*)d_in[3];
    const float* bih    = (const float*)d_in[4];
    const float* bhh    = (const float*)d_in[5];
    float* out = (float*)d_out;

    float* ix    = (float*)d_ws;                                     // 33.55 MB
    u32_t* hslot = (u32_t*)((char*)d_ws + (size_t)S_LEN * GDIM * 4); // 8 MB
    // total ws use: 41.9 MB

    dim3 gA(S_LEN / 64, GDIM / 64);
    hipLaunchKernelGGL(ix_gemm, gA, dim3(256), 0, stream,
                       tokens, emb, Wih, bih, bhh, ix);
    hipLaunchKernelGGL(lstm_rec, dim3(1024), dim3(256), 0, stream,
                       Whh, ix, hslot, out);
}

// Round 6
// 6002.663 us; speedup vs baseline: 3.0207x; 3.0207x over previous
//
#include <hip/hip_runtime.h>

typedef unsigned int u32_t;

#define S_LEN 2048
#define EDIM  1024
#define HDIM  1024
#define GDIM  4096   // 4*H

#define POISON 0xAAAAAAAAu

// ---------------------------------------------------------------------------
// Phase A: ix[t][r] = emb[tokens[t]] . W_ih[r] + b_ih[r] + b_hh[r]
// fp32 LDS-tiled GEMM, 64x64 tile, BK=16, 256 threads, 4x4 micro-tile. ~92us.
// (unchanged from the passing R2 kernel)
// ---------------------------------------------------------------------------
__global__ __launch_bounds__(256)
void ix_gemm(const int* __restrict__ tokens, const float* __restrict__ emb,
             const float* __restrict__ Wih, const float* __restrict__ bih,
             const float* __restrict__ bhh, float* __restrict__ ix)
{
    __shared__ float As[16][68];
    __shared__ float Bs[16][68];
    const int t0  = blockIdx.x * 64;
    const int r0  = blockIdx.y * 64;
    const int tid = threadIdx.x;
    const int tx  = tid & 15;          // n-direction
    const int ty  = tid >> 4;          // m-direction
    const int m_a = tid & 63;          // staging row
    const int k_a = (tid >> 6) << 2;   // staging k offset: 0,4,8,12

    const float* arow = emb + (size_t)tokens[t0 + m_a] * EDIM + k_a;
    const float* brow = Wih + (size_t)(r0 + m_a) * EDIM + k_a;

    float acc[4][4] = {};
    for (int kk = 0; kk < EDIM; kk += 16) {
        float4 av = *(const float4*)(arow + kk);
        float4 bv = *(const float4*)(brow + kk);
        __syncthreads();
        As[k_a + 0][m_a] = av.x; As[k_a + 1][m_a] = av.y;
        As[k_a + 2][m_a] = av.z; As[k_a + 3][m_a] = av.w;
        Bs[k_a + 0][m_a] = bv.x; Bs[k_a + 1][m_a] = bv.y;
        Bs[k_a + 2][m_a] = bv.z; Bs[k_a + 3][m_a] = bv.w;
        __syncthreads();
#pragma unroll
        for (int k = 0; k < 16; ++k) {
            float4 a = *(const float4*)&As[k][ty << 2];
            float4 b = *(const float4*)&Bs[k][tx << 2];
            acc[0][0] += a.x * b.x; acc[0][1] += a.x * b.y;
            acc[0][2] += a.x * b.z; acc[0][3] += a.x * b.w;
            acc[1][0] += a.y * b.x; acc[1][1] += a.y * b.y;
            acc[1][2] += a.y * b.z; acc[1][3] += a.y * b.w;
            acc[2][0] += a.z * b.x; acc[2][1] += a.z * b.y;
            acc[2][2] += a.z * b.z; acc[2][3] += a.z * b.w;
            acc[3][0] += a.w * b.x; acc[3][1] += a.w * b.y;
            acc[3][2] += a.w * b.z; acc[3][3] += a.w * b.w;
        }
    }
    const int n0 = r0 + (tx << 2);
    float b0 = bih[n0 + 0] + bhh[n0 + 0];
    float b1 = bih[n0 + 1] + bhh[n0 + 1];
    float b2 = bih[n0 + 2] + bhh[n0 + 2];
    float b3 = bih[n0 + 3] + bhh[n0 + 3];
#pragma unroll
    for (int i = 0; i < 4; ++i) {
        int m = t0 + (ty << 2) + i;
        float4 v = make_float4(acc[i][0] + b0, acc[i][1] + b1,
                               acc[i][2] + b2, acc[i][3] + b3);
        *(float4*)(ix + (size_t)m * GDIM + n0) = v;
    }
}

// ---------------------------------------------------------------------------
// Phase B: persistent recurrence, R2 shape (best measured: 3.08 us/step):
// 256 blocks x 256 threads = 1 block/CU, 4 waves. Wave w computes gate rows
// {j, H+j, 2H+j, 3H+j}, j = 4*block + w.
//
// NEW vs R2: weights live in LDS (64 KB staged once), read per step as
// conflict-free ds_read_b128 (16B lane stride). This removes the
// 16.8 MB/step device-wide L2/HBM weight re-fetch that R2-R4's VGPR=52
// proved the allocator forces (it will not hold 64 weight floats/lane,
// regardless of launch_bounds or asm pins — three rounds of evidence).
//
// Hand-off: hslot[t][j] plain fp32, written once; d_ws pre-poisoned
// 0xAAAAAAAA by the harness, so "ready" == bits != POISON. Producer
// canonicalizes exact-poison h to 0.0f (err 3e-13, hang-proof). Thread tid
// polls the 4 dwords [4*tid..4*tid+3] with sticky per-dword retries +
// s_sleep throttle; a speculative prefetch right after the store hides one
// fabric round trip. hs[] double-buffered -> ONE barrier per step.
// ---------------------------------------------------------------------------
__device__ __forceinline__ float fast_sigmoid(float x) {
    return 1.0f / (1.0f + __expf(-x));
}
__device__ __forceinline__ float fast_tanh(float x) {
    return 1.0f - 2.0f / (__expf(2.0f * x) + 1.0f);
}

__global__ __launch_bounds__(256)
void lstm_rec(const float* __restrict__ Whh,   // [4H, H]
              const float* __restrict__ ix,    // [S, 4H]
              u32_t* hslot,                    // [S][H] poison-init
              float* __restrict__ out)         // [H]
{
    const int tid  = threadIdx.x;
    const int wid  = tid >> 6;                 // 0..3
    const int lane = tid & 63;
    const int b    = blockIdx.x;
    const int j    = b * 4 + wid;              // 0..1023

    __shared__ float wlds[4][4][HDIM];         // 64 KB: [wave][gate][k]
    __shared__ float hs[2][HDIM];              // 8 KB, double-buffered

    // Stage weights once: 16 rows x 4KB, float4-coalesced.
#pragma unroll
    for (int w = 0; w < 4; ++w)
#pragma unroll
        for (int g = 0; g < 4; ++g) {
            const float* row = Whh + (size_t)(g * HDIM + b * 4 + w) * HDIM;
            *(float4*)&wlds[w][g][tid << 2] = *(const float4*)(row + (tid << 2));
        }
    __syncthreads();

    float c = 0.0f;
    u32_t p0 = POISON, p1 = POISON, p2 = POISON, p3 = POISON;

    for (int t = 0; t < S_LEN; ++t) {
        // ix contributions (wave-uniform); issued early, consumed post-reduce.
        const float* ixt = ix + (size_t)t * GDIM;
        float bi = ixt[j];
        float bf = ixt[HDIM + j];
        float bg = ixt[2 * HDIM + j];
        float bo = ixt[3 * HDIM + j];

        const int buf = t & 1;
        if (t == 0) {
            *(float4*)&hs[0][tid << 2] = make_float4(0.f, 0.f, 0.f, 0.f);
        } else {
            const u32_t* src = hslot + (size_t)(t - 1) * HDIM + (tid << 2);
            for (;;) {
                bool m0 = (p0 == POISON), m1 = (p1 == POISON);
                bool m2 = (p2 == POISON), m3 = (p3 == POISON);
                if (!(m0 | m1 | m2 | m3)) break;
                if (m0) p0 = __hip_atomic_load(src + 0, __ATOMIC_RELAXED, __HIP_MEMORY_SCOPE_AGENT);
                if (m1) p1 = __hip_atomic_load(src + 1, __ATOMIC_RELAXED, __HIP_MEMORY_SCOPE_AGENT);
                if (m2) p2 = __hip_atomic_load(src + 2, __ATOMIC_RELAXED, __HIP_MEMORY_SCOPE_AGENT);
                if (m3) p3 = __hip_atomic_load(src + 3, __ATOMIC_RELAXED, __HIP_MEMORY_SCOPE_AGENT);
                __builtin_amdgcn_s_sleep(1);   // throttle fabric poll storm
            }
            *(float4*)&hs[buf][tid << 2] =
                make_float4(__uint_as_float(p0), __uint_as_float(p1),
                            __uint_as_float(p2), __uint_as_float(p3));
        }
        __syncthreads();   // single barrier/step (hs double-buffered)

        // 4 gates x 16 k-elements per lane; weights + h via ds_read_b128.
        float4 h0 = *(const float4*)&hs[buf][0 * 256 + (lane << 2)];
        float4 h1 = *(const float4*)&hs[buf][1 * 256 + (lane << 2)];
        float4 h2 = *(const float4*)&hs[buf][2 * 256 + (lane << 2)];
        float4 h3 = *(const float4*)&hs[buf][3 * 256 + (lane << 2)];

        float s[4];
#pragma unroll
        for (int g = 0; g < 4; ++g) {
            float4 w0 = *(const float4*)&wlds[wid][g][0 * 256 + (lane << 2)];
            float4 w1 = *(const float4*)&wlds[wid][g][1 * 256 + (lane << 2)];
            float4 w2 = *(const float4*)&wlds[wid][g][2 * 256 + (lane << 2)];
            float4 w3 = *(const float4*)&wlds[wid][g][3 * 256 + (lane << 2)];
            s[g] = w0.x*h0.x + w0.y*h0.y + w0.z*h0.z + w0.w*h0.w
                 + w1.x*h1.x + w1.y*h1.y + w1.z*h1.z + w1.w*h1.w
                 + w2.x*h2.x + w2.y*h2.y + w2.z*h2.z + w2.w*h2.w
                 + w3.x*h3.x + w3.y*h3.y + w3.z*h3.z + w3.w*h3.w;
        }

        // 64-lane butterfly all-reduce, 4 interleaved chains.
#pragma unroll
        for (int sh = 32; sh > 0; sh >>= 1) {
            s[0] += __shfl_xor(s[0], sh, 64);
            s[1] += __shfl_xor(s[1], sh, 64);
            s[2] += __shfl_xor(s[2], sh, 64);
            s[3] += __shfl_xor(s[3], sh, 64);
        }

        float si = s[0] + bi, sf = s[1] + bf, sg = s[2] + bg, so = s[3] + bo;
        float ig = fast_sigmoid(si);
        float fg = fast_sigmoid(sf);
        float og = fast_sigmoid(so);
        float gt = fast_tanh(sg);
        c = fg * c + ig * gt;                  // redundant across lanes (consistent)
        float h = og * fast_tanh(c);

        if (lane == 0) {
            u32_t hb = __float_as_uint(h);
            if (hb == POISON) hb = 0u;         // hang-proof canonicalization
            __hip_atomic_store(hslot + (size_t)t * HDIM + j, hb,
                               __ATOMIC_RELAXED, __HIP_MEMORY_SCOPE_AGENT);
            if (t == S_LEN - 1) out[j] = h;
        }

        // Speculative prefetch of next step's 4 dwords; stragglers re-polled
        // at the top of the next iteration.
        const u32_t* nsrc = hslot + (size_t)t * HDIM + (tid << 2);
        p0 = __hip_atomic_load(nsrc + 0, __ATOMIC_RELAXED, __HIP_MEMORY_SCOPE_AGENT);
        p1 = __hip_atomic_load(nsrc + 1, __ATOMIC_RELAXED, __HIP_MEMORY_SCOPE_AGENT);
        p2 = __hip_atomic_load(nsrc + 2, __ATOMIC_RELAXED, __HIP_MEMORY_SCOPE_AGENT);
        p3 = __hip_atomic_load(nsrc + 3, __ATOMIC_RELAXED, __HIP_MEMORY_SCOPE_AGENT);
        // No trailing barrier: hs double-buffered; a wave is at most one
        // barrier ahead and writes only the other buffer.
    }
}

// ---------------------------------------------------------------------------
extern "C" void kernel_launch(void* const* d_in, const int* in_sizes, int n_in,
                              void* d_out, int out_size, void* d_ws, size_t ws_size,
                              hipStream_t stream) {
    const int*   tokens = (const int*)  d_in[0];
    const float* emb    = (const float*)d_in[1];
    const float* Wih    = (const float*)d_in[2];
    const float* Whh    = (const float*)d_in[3];
    const float* bih    = (const float*)d_in[4];
    const float* bhh    = (const float*)d_in[5];
    float* out = (float*)d_out;

    float* ix    = (float*)d_ws;                                     // 33.55 MB
    u32_t* hslot = (u32_t*)((char*)d_ws + (size_t)S_LEN * GDIM * 4); // 8 MB
    // total ws use: 41.9 MB

    dim3 gA(S_LEN / 64, GDIM / 64);
    hipLaunchKernelGGL(ix_gemm, gA, dim3(256), 0, stream,
                       tokens, emb, Wih, bih, bhh, ix);
    hipLaunchKernelGGL(lstm_rec, dim3(256), dim3(256), 0, stream,
                       Whh, ix, hslot, out);
}